// Round 1
// baseline (848.047 us; speedup 1.0000x reference)
//
#include <hip/hip_runtime.h>
#include <hip/hip_bf16.h>

#define F_IN 512

// --- degree count over col (int atomics) ---
__global__ void k_deg(const int* __restrict__ col, int* __restrict__ deg, int E) {
    int i = blockIdx.x * blockDim.x + threadIdx.x;
    if (i < E) atomicAdd(&deg[col[i]], 1);
}

// --- dinv = rsqrt(deg + 1)   (in-place int -> float) ---
__global__ void k_dinv(float* __restrict__ buf, int n) {
    int i = blockIdx.x * blockDim.x + threadIdx.x;
    if (i < n) {
        int d = ((const int*)buf)[i] + 1;   // +1 self-loop
        buf[i] = rsqrtf((float)d);
    }
}

// --- hs = (x @ W1) * dinv[node];  acc initialized to hs (self-loop term) ---
// wave-per-node; W1 (512x16) held in 128 VGPRs per lane; butterfly reduce.
__global__ __launch_bounds__(256) void k_gemm1(
    const float* __restrict__ x, const float* __restrict__ W1,
    const float* __restrict__ dinv, float* __restrict__ hs,
    float* __restrict__ acc, int n)
{
    const int lane = threadIdx.x & 63;
    const int wave = blockIdx.x * (blockDim.x >> 6) + (threadIdx.x >> 6);
    const int nw   = gridDim.x * (blockDim.x >> 6);

    // lane l holds W1 rows k = 8l .. 8l+7, all 16 cols -> 128 floats
    float w[128];
    #pragma unroll
    for (int i = 0; i < 32; ++i) {
        float4 t = ((const float4*)W1)[lane * 32 + i];
        w[4*i+0] = t.x; w[4*i+1] = t.y; w[4*i+2] = t.z; w[4*i+3] = t.w;
    }

    for (int node = wave; node < n; node += nw) {
        const float4* xr = (const float4*)(x + (size_t)node * F_IN);
        float4 a = xr[lane * 2];
        float4 b = xr[lane * 2 + 1];
        float xs[8] = {a.x, a.y, a.z, a.w, b.x, b.y, b.z, b.w};

        float p[16];
        #pragma unroll
        for (int j = 0; j < 16; ++j) p[j] = 0.f;
        #pragma unroll
        for (int i = 0; i < 8; ++i)
            #pragma unroll
            for (int j = 0; j < 16; ++j)
                p[j] = fmaf(xs[i], w[i * 16 + j], p[j]);

        #pragma unroll
        for (int off = 32; off >= 1; off >>= 1)
            #pragma unroll
            for (int j = 0; j < 16; ++j)
                p[j] += __shfl_down(p[j], off);

        if (lane == 0) {
            float s = dinv[node];
            float4* ho = (float4*)(hs  + node * 16);
            float4* ao = (float4*)(acc + node * 16);
            #pragma unroll
            for (int q = 0; q < 4; ++q) {
                float4 v = make_float4(p[4*q+0]*s, p[4*q+1]*s, p[4*q+2]*s, p[4*q+3]*s);
                ho[q] = v;
                ao[q] = v;
            }
        }
    }
}

// --- acc[col[e]][j] += hs[row[e]][j], 16 threads per edge ---
__global__ void k_scatter(const int* __restrict__ row, const int* __restrict__ col,
                          const float* __restrict__ hs, float* __restrict__ acc, int E)
{
    int t = blockIdx.x * blockDim.x + threadIdx.x;
    int e = t >> 4;
    if (e < E) {
        int j = t & 15;
        int r = row[e], c = col[e];
        atomicAdd(&acc[c * 16 + j], hs[r * 16 + j]);
    }
}

// --- layer-2: out1 = relu(acc*dinv + b1); h2s = (out1 @ W2) * dinv ---
// 16 lanes per node; acc (C) overwritten in place after read -> acc2 init.
__global__ void k_gemm2(float* __restrict__ acc, float* __restrict__ hs2,
                        const float* __restrict__ dinv,
                        const float* __restrict__ b1, const float* __restrict__ W2,
                        int n)
{
    int t = blockIdx.x * blockDim.x + threadIdx.x;
    int node = t >> 4, j = t & 15;
    if (node >= n) return;
    float di = dinv[node];
    float v = fmaxf(acc[node * 16 + j] * di + b1[j], 0.f);
    float h2 = 0.f;
    #pragma unroll
    for (int k = 0; k < 16; ++k) {
        float ok = __shfl(v, k, 16);
        h2 = fmaf(ok, W2[k * 16 + j], h2);
    }
    float o = h2 * di;
    hs2[node * 16 + j] = o;
    acc[node * 16 + j] = o;
}

// --- final: v = acc*dinv + b2; log_softmax over 16 classes ---
__global__ void k_final(const float* __restrict__ acc, const float* __restrict__ dinv,
                        const float* __restrict__ b2, float* __restrict__ out, int n)
{
    int t = blockIdx.x * blockDim.x + threadIdx.x;
    int node = t >> 4, j = t & 15;
    if (node >= n) return;
    float v = acc[node * 16 + j] * dinv[node] + b2[j];
    float m = v;
    #pragma unroll
    for (int off = 8; off >= 1; off >>= 1) m = fmaxf(m, __shfl_xor(m, off));
    float e = expf(v - m);
    float s = e;
    #pragma unroll
    for (int off = 8; off >= 1; off >>= 1) s += __shfl_xor(s, off);
    out[node * 16 + j] = v - m - logf(s);
}

extern "C" void kernel_launch(void* const* d_in, const int* in_sizes, int n_in,
                              void* d_out, int out_size, void* d_ws, size_t ws_size,
                              hipStream_t stream)
{
    const float* x  = (const float*)d_in[0];
    const int*   ei = (const int*)d_in[1];   // [2, E] int32: row then col
    const float* W1 = (const float*)d_in[2];
    const float* b1 = (const float*)d_in[3];
    const float* W2 = (const float*)d_in[4];
    const float* b2 = (const float*)d_in[5];
    float* out = (float*)d_out;

    const int n = in_sizes[0] / F_IN;       // 100000
    const int E = in_sizes[1] / 2;          // 3.2M

    // workspace layout (reused across layers):
    //   A: n floats   — deg(int) then dinv
    //   B: n*16 float — hs1, then hs2
    //   C: n*16 float — acc1, then acc2 (overwritten in place by k_gemm2)
    char* ws = (char*)d_ws;
    size_t offA = 0;
    size_t szA  = (((size_t)n * 4) + 511) & ~(size_t)511;
    float* A = (float*)(ws + offA);
    float* B = (float*)(ws + szA);
    float* C = (float*)(ws + szA + (size_t)n * 16 * 4);

    hipMemsetAsync(A, 0, (size_t)n * sizeof(int), stream);
    k_deg <<<(E + 255) / 256, 256, 0, stream>>>(ei + E, (int*)A, E);
    k_dinv<<<(n + 255) / 256, 256, 0, stream>>>(A, n);

    // layer 1
    k_gemm1  <<<2048, 256, 0, stream>>>(x, W1, A, B, C, n);
    k_scatter<<<(E * 16 + 255) / 256, 256, 0, stream>>>(ei, ei + E, B, C, E);

    // layer 2
    k_gemm2  <<<(n * 16 + 255) / 256, 256, 0, stream>>>(C, B, A, b1, W2, n);
    k_scatter<<<(E * 16 + 255) / 256, 256, 0, stream>>>(ei, ei + E, B, C, E);

    // epilogue
    k_final  <<<(n * 16 + 255) / 256, 256, 0, stream>>>(C, A, b2, out, n);
}

// Round 2
// 823.869 us; speedup vs baseline: 1.0293x; 1.0293x over previous
//
#include <hip/hip_runtime.h>
#include <hip/hip_bf16.h>

#define F_IN 512

// --- in-degree count over col (int atomics) ---
__global__ void k_deg(const int* __restrict__ col, int* __restrict__ deg, int E) {
    int i = blockIdx.x * blockDim.x + threadIdx.x;
    if (i < E) atomicAdd(&deg[col[i]], 1);
}

// --- scan stage 1: per-block exclusive scan of deg -> pos; block sums -> bsum ---
__global__ void k_scan1(const int* __restrict__ deg, int* __restrict__ pos,
                        int* __restrict__ bsum, int n) {
    __shared__ int sm[256];
    int t = threadIdx.x, i = blockIdx.x * 256 + t;
    int v = (i < n) ? deg[i] : 0;
    sm[t] = v; __syncthreads();
    #pragma unroll
    for (int off = 1; off < 256; off <<= 1) {
        int xv = (t >= off) ? sm[t - off] : 0;
        __syncthreads();
        sm[t] += xv; __syncthreads();
    }
    if (i < n) pos[i] = sm[t] - v;          // exclusive within block
    if (t == 255) bsum[blockIdx.x] = sm[255];
}

// --- scan stage 2: exclusive scan of block sums (nb <= 512) ---
__global__ void k_scan2(int* __restrict__ bsum, int nb) {
    __shared__ int sm[512];
    int t = threadIdx.x;
    int v = (t < nb) ? bsum[t] : 0;
    sm[t] = v; __syncthreads();
    #pragma unroll
    for (int off = 1; off < 512; off <<= 1) {
        int xv = (t >= off) ? sm[t - off] : 0;
        __syncthreads();
        sm[t] += xv; __syncthreads();
    }
    if (t < nb) bsum[t] = sm[t] - v;        // exclusive
}

// --- scan stage 3: add block offsets; also dinv = rsqrt(deg+1) ---
__global__ void k_scan3(int* __restrict__ pos, const int* __restrict__ bsum,
                        const int* __restrict__ deg, float* __restrict__ dinv, int n) {
    int i = blockIdx.x * 256 + threadIdx.x;
    if (i < n) {
        pos[i] += bsum[blockIdx.x];
        dinv[i] = rsqrtf((float)(deg[i] + 1));   // +1 self-loop
    }
}

// --- bin source ids by destination bucket; pos[i] ends at bucket END ---
__global__ void k_bin(const int* __restrict__ row, const int* __restrict__ col,
                      int* __restrict__ pos, int* __restrict__ srcs, int E) {
    int e = blockIdx.x * 256 + threadIdx.x;
    if (e < E) {
        int p = atomicAdd(&pos[col[e]], 1);
        srcs[p] = row[e];
    }
}

// --- hs = (x @ W1) * dinv[node], wave-per-node, LDS transpose-reduce ---
__global__ __launch_bounds__(256) void k_gemm1(
    const float* __restrict__ x, const float* __restrict__ W1,
    const float* __restrict__ dinv, float* __restrict__ hs, int n)
{
    __shared__ float red[4][64 * 17];       // pad 17: write/read both 2-way (free)
    const int lane = threadIdx.x & 63;
    const int wib  = threadIdx.x >> 6;
    const int wave = blockIdx.x * (blockDim.x >> 6) + wib;
    const int nw   = gridDim.x * (blockDim.x >> 6);
    float* rb = red[wib];

    // lane l holds W1 rows k = 8l .. 8l+7, all 16 cols -> 128 VGPRs
    float w[128];
    #pragma unroll
    for (int i = 0; i < 32; ++i) {
        float4 t = ((const float4*)W1)[lane * 32 + i];
        w[4*i+0] = t.x; w[4*i+1] = t.y; w[4*i+2] = t.z; w[4*i+3] = t.w;
    }
    const int q  = lane >> 4;
    const int jj = lane & 15;

    for (int node = wave; node < n; node += nw) {
        const float4* xr = (const float4*)(x + (size_t)node * F_IN);
        float4 a = xr[lane * 2];
        float4 b = xr[lane * 2 + 1];
        float xs[8] = {a.x, a.y, a.z, a.w, b.x, b.y, b.z, b.w};

        float p[16];
        #pragma unroll
        for (int j = 0; j < 16; ++j) p[j] = 0.f;
        #pragma unroll
        for (int i = 0; i < 8; ++i)
            #pragma unroll
            for (int j = 0; j < 16; ++j)
                p[j] = fmaf(xs[i], w[i * 16 + j], p[j]);

        // transpose-reduce through LDS (single wave, no barrier needed)
        #pragma unroll
        for (int j = 0; j < 16; ++j) rb[lane * 17 + j] = p[j];
        __asm__ volatile("s_waitcnt lgkmcnt(0)" ::: "memory");
        float s = 0.f;
        #pragma unroll
        for (int i = 0; i < 16; ++i) s += rb[(q * 16 + i) * 17 + jj];
        s += __shfl_down(s, 32);
        s += __shfl_down(s, 16);
        if (lane < 16) hs[node * 16 + jj] = s * dinv[node];
    }
}

// --- pull aggregation: acc[c] = hs[c] + sum_{r in in(c)} hs[r] ---
__global__ void k_gather(const int* __restrict__ srcs, const int* __restrict__ pos,
                         const int* __restrict__ deg, const float* __restrict__ hs,
                         float* __restrict__ acc, int n)
{
    int t = blockIdx.x * 256 + threadIdx.x;
    int node = t >> 4, j = t & 15;
    if (node >= n) return;
    int cnt   = deg[node];
    int start = pos[node] - cnt;            // pos is bucket END after k_bin
    const int* sp = srcs + start;
    float s = hs[node * 16 + j];            // self-loop term
    int i = 0;
    for (; i + 4 <= cnt; i += 4) {
        int s0 = sp[i], s1 = sp[i+1], s2 = sp[i+2], s3 = sp[i+3];
        float v0 = hs[s0 * 16 + j];
        float v1 = hs[s1 * 16 + j];
        float v2 = hs[s2 * 16 + j];
        float v3 = hs[s3 * 16 + j];
        s += v0 + v1 + v2 + v3;
    }
    for (; i < cnt; ++i) s += hs[sp[i] * 16 + j];
    acc[node * 16 + j] = s;
}

// --- layer-2: v = relu(acc*dinv + b1); hs2 = (v @ W2) * dinv ---
__global__ void k_gemm2(const float* __restrict__ acc, float* __restrict__ hs2,
                        const float* __restrict__ dinv,
                        const float* __restrict__ b1, const float* __restrict__ W2,
                        int n)
{
    int t = blockIdx.x * blockDim.x + threadIdx.x;
    int node = t >> 4, j = t & 15;
    if (node >= n) return;
    float di = dinv[node];
    float v = fmaxf(acc[node * 16 + j] * di + b1[j], 0.f);
    float h2 = 0.f;
    #pragma unroll
    for (int k = 0; k < 16; ++k) {
        float ok = __shfl(v, k, 16);
        h2 = fmaf(ok, W2[k * 16 + j], h2);
    }
    hs2[node * 16 + j] = h2 * di;
}

// --- final: v = acc*dinv + b2; log_softmax over 16 classes (in-place on out) ---
__global__ void k_final(const float* __restrict__ acc, const float* __restrict__ dinv,
                        const float* __restrict__ b2, float* __restrict__ out, int n)
{
    int t = blockIdx.x * blockDim.x + threadIdx.x;
    int node = t >> 4, j = t & 15;
    if (node >= n) return;
    float v = acc[node * 16 + j] * dinv[node] + b2[j];
    float m = v;
    #pragma unroll
    for (int off = 8; off >= 1; off >>= 1) m = fmaxf(m, __shfl_xor(m, off));
    float e = expf(v - m);
    float s = e;
    #pragma unroll
    for (int off = 8; off >= 1; off >>= 1) s += __shfl_xor(s, off);
    out[node * 16 + j] = v - m - logf(s);
}

extern "C" void kernel_launch(void* const* d_in, const int* in_sizes, int n_in,
                              void* d_out, int out_size, void* d_ws, size_t ws_size,
                              hipStream_t stream)
{
    const float* x  = (const float*)d_in[0];
    const int*   ei = (const int*)d_in[1];   // [2, E]: row then col
    const float* W1 = (const float*)d_in[2];
    const float* b1 = (const float*)d_in[3];
    const float* W2 = (const float*)d_in[4];
    const float* b2 = (const float*)d_in[5];
    float* out = (float*)d_out;

    const int n = in_sizes[0] / F_IN;        // 100000
    const int E = in_sizes[1] / 2;           // 3.2M
    const int G1 = (n + 255) / 256;          // 391 (<= 512 for k_scan2)

    // workspace layout (d_out doubles as the aggregation accumulator):
    char* ws = (char*)d_ws;
    size_t szN = (((size_t)n * 4) + 511) & ~(size_t)511;
    int*   deg  = (int*)(ws);
    int*   pos  = (int*)(ws + szN);
    float* dinv = (float*)(ws + 2 * szN);
    int*   bsum = (int*)(ws + 3 * szN);                 // 512 ints
    int*   srcs = (int*)(ws + 3 * szN + 2048);
    float* hs   = (float*)(ws + 3 * szN + 2048 + (((size_t)E * 4 + 511) & ~(size_t)511));
    float* acc  = out;

    hipMemsetAsync(deg, 0, (size_t)n * sizeof(int), stream);
    k_deg  <<<(E + 255) / 256, 256, 0, stream>>>(ei + E, deg, E);
    k_scan1<<<G1, 256, 0, stream>>>(deg, pos, bsum, n);
    k_scan2<<<1, 512, 0, stream>>>(bsum, G1);
    k_scan3<<<G1, 256, 0, stream>>>(pos, bsum, deg, dinv, n);
    k_bin  <<<(E + 255) / 256, 256, 0, stream>>>(ei, ei + E, pos, srcs, E);

    // layer 1
    k_gemm1 <<<2048, 256, 0, stream>>>(x, W1, dinv, hs, n);
    k_gather<<<(n * 16 + 255) / 256, 256, 0, stream>>>(srcs, pos, deg, hs, acc, n);

    // layer 2
    k_gemm2 <<<(n * 16 + 255) / 256, 256, 0, stream>>>(acc, hs, dinv, b1, W2, n);
    k_gather<<<(n * 16 + 255) / 256, 256, 0, stream>>>(srcs, pos, deg, hs, acc, n);

    // epilogue
    k_final <<<(n * 16 + 255) / 256, 256, 0, stream>>>(acc, dinv, b2, out, n);
}